// Round 1
// baseline (42.603 us; speedup 1.0000x reference)
//
#include <hip/hip_runtime.h>
#include <math.h>

// cov = R(q) * diag(exp(clip(s,-10,2))^2) * R(q)^T  per gaussian.
// scales: (N,3) f32, rotations: (N,4) f32, out: (N,3,3) f32.
// Memory-bound: 28B in + 36B out per gaussian -> coalescing is everything.

constexpr int TPB = 256;

__device__ __forceinline__ void compute_cov(float s0, float s1, float s2,
                                            float qw, float qx, float qy, float qz,
                                            float cov[9])
{
    // s = exp(clip(scale, -10, 2)); a,b,c = s^2
    float e0 = expf(fminf(fmaxf(s0, -10.0f), 2.0f));
    float e1 = expf(fminf(fmaxf(s1, -10.0f), 2.0f));
    float e2 = expf(fminf(fmaxf(s2, -10.0f), 2.0f));
    float a = e0 * e0, b = e1 * e1, c = e2 * e2;

    // first normalize: q / (||q|| + 1e-8)
    float nrm = sqrtf(qw*qw + qx*qx + qy*qy + qz*qz);
    float inv = 1.0f / (nrm + 1e-8f);
    float w = qw * inv, x = qx * inv, y = qy * inv, z = qz * inv;
    // second normalize (reference normalizes again inside quat_to_rotmat)
    float inv2 = rsqrtf(w*w + x*x + y*y + z*z);
    w *= inv2; x *= inv2; y *= inv2; z *= inv2;

    float r00 = 1.0f - 2.0f * (y*y + z*z);
    float r01 = 2.0f * (x*y - w*z);
    float r02 = 2.0f * (x*z + w*y);
    float r10 = 2.0f * (x*y + w*z);
    float r11 = 1.0f - 2.0f * (x*x + z*z);
    float r12 = 2.0f * (y*z - w*x);
    float r20 = 2.0f * (x*z - w*y);
    float r21 = 2.0f * (y*z + w*x);
    float r22 = 1.0f - 2.0f * (x*x + y*y);

    // cov[i][k] = sum_j R[i][j] * s2[j] * R[k][j]  (symmetric)
    float m00 = r00 * a, m01 = r01 * b, m02 = r02 * c;
    float m10 = r10 * a, m11 = r11 * b, m12 = r12 * c;
    float m20 = r20 * a, m21 = r21 * b, m22 = r22 * c;

    cov[0] = m00*r00 + m01*r01 + m02*r02;
    cov[1] = m00*r10 + m01*r11 + m02*r12;
    cov[2] = m00*r20 + m01*r21 + m02*r22;
    cov[3] = cov[1];
    cov[4] = m10*r10 + m11*r11 + m12*r12;
    cov[5] = m10*r20 + m11*r21 + m12*r22;
    cov[6] = cov[2];
    cov[7] = cov[5];
    cov[8] = m20*r20 + m21*r21 + m22*r22;
}

__global__ __launch_bounds__(TPB) void gaussian_cov_kernel(
    const float* __restrict__ scales,
    const float4* __restrict__ rots,
    float4* __restrict__ out4,
    float* __restrict__ out,
    int n)
{
    __shared__ float sm_s[3 * TPB];   // staged scales
    __shared__ float sm_c[9 * TPB];   // staged covariances

    const int t = threadIdx.x;
    const int base = blockIdx.x * TPB;

    if (base + TPB <= n) {
        // ---- fast path: full tile of 256 gaussians ----
        // 1. stage scales: 768 floats = 192 float4, fully coalesced
        {
            const float4* sp = reinterpret_cast<const float4*>(scales) + (size_t)base * 3 / 4;
            if (t < (3 * TPB) / 4) {
                reinterpret_cast<float4*>(sm_s)[t] = sp[t];
            }
        }
        // 2. rotation: one float4 per lane, fully coalesced
        float4 q = rots[base + t];
        __syncthreads();

        float s0 = sm_s[3 * t + 0];
        float s1 = sm_s[3 * t + 1];
        float s2 = sm_s[3 * t + 2];

        float cov[9];
        compute_cov(s0, s1, s2, q.x, q.y, q.z, q.w, cov);

        // 3. write into LDS, stride 9 (gcd(9,32)=1 -> conflict-free)
        #pragma unroll
        for (int k = 0; k < 9; ++k) sm_c[9 * t + k] = cov[k];
        __syncthreads();

        // 4. drain: 2304 floats = 576 float4, fully coalesced
        float4* dst = out4 + (size_t)base * 9 / 4;
        const float4* src = reinterpret_cast<const float4*>(sm_c);
        #pragma unroll
        for (int idx = t; idx < (9 * TPB) / 4; idx += TPB) {
            dst[idx] = src[idx];
        }
    } else {
        // ---- tail path (N % 256 != 0 safety; unused for N = 4e6) ----
        int i = base + t;
        if (i < n) {
            float s0 = scales[3 * i + 0];
            float s1 = scales[3 * i + 1];
            float s2 = scales[3 * i + 2];
            float4 q = rots[i];
            float cov[9];
            compute_cov(s0, s1, s2, q.x, q.y, q.z, q.w, cov);
            #pragma unroll
            for (int k = 0; k < 9; ++k) out[(size_t)i * 9 + k] = cov[k];
        }
    }
}

extern "C" void kernel_launch(void* const* d_in, const int* in_sizes, int n_in,
                              void* d_out, int out_size, void* d_ws, size_t ws_size,
                              hipStream_t stream)
{
    const float*  scales = reinterpret_cast<const float*>(d_in[0]);
    const float4* rots   = reinterpret_cast<const float4*>(d_in[1]);
    float* out = reinterpret_cast<float*>(d_out);

    const int n = in_sizes[0] / 3;   // 4,000,000
    const int blocks = (n + TPB - 1) / TPB;

    gaussian_cov_kernel<<<blocks, TPB, 0, stream>>>(
        scales, rots, reinterpret_cast<float4*>(out), out, n);
}